// Round 4
// baseline (435.053 us; speedup 1.0000x reference)
//
#include <hip/hip_runtime.h>
#include <hip/hip_bf16.h>

// ---------------------------------------------------------------------------
// LinearAttentionBlock: Q=phi(xWq+bq), K=phi(xWk+bk), V=xWv+bv
// scores = tril(Q K^T); out = ((scores V) / (rowsum(scores)+eps)) Wo + bo
// GEMMs: 8-phase 256x256 tile, BK=64, 8 waves (2Mx4N), bf16 mfma 16x16x32.
// Quarter-granular (64-row unit) staging: every global_load_lds has >=6
// phases of issue-to-use slack; one vmcnt(8) per K-tile (never 0 in loop).
// T2 XOR swizzle (pre-swizzled global src, swizzled ds_read) + T5 setprio.
// ---------------------------------------------------------------------------

#define D_MODEL 1024
#define D_INNER 2048
#define SEQ     2048
#define NBATCH  4
#define MTOT    (NBATCH * SEQ)   // 8192

typedef __attribute__((ext_vector_type(8))) __bf16 bf16x8;
typedef __attribute__((ext_vector_type(4))) float  f32x4;
typedef __attribute__((ext_vector_type(8))) short  short8v;

__device__ __forceinline__ short f2bf(float f) {      // RNE f32 -> bf16 bits
  union { float f; unsigned u; } x; x.f = f;
  unsigned r = x.u + 0x7fffu + ((x.u >> 16) & 1u);
  return (short)(r >> 16);
}
__device__ __forceinline__ float bf2f(short s) {
  union { unsigned u; float f; } x; x.u = ((unsigned)(unsigned short)s) << 16;
  return x.f;
}

typedef const void __attribute__((address_space(1)))* as1cv;
typedef void __attribute__((address_space(3)))* as3v;

__device__ __forceinline__ void gload_lds16(const void* g, void* l) {
  __builtin_amdgcn_global_load_lds((as1cv)g, (as3v)l, 16, 0, 0);
}

__device__ __forceinline__ f32x4 mfmaOp(bf16x8 a, bf16x8 b, f32x4 c) {
  return __builtin_amdgcn_mfma_f32_16x16x32_bf16(a, b, c, 0, 0, 0);
}

#define BARRIER __builtin_amdgcn_s_barrier()
#define LGKM0   asm volatile("s_waitcnt lgkmcnt(0)" ::: "memory")
#define VMCNT8  asm volatile("s_waitcnt vmcnt(8)" ::: "memory")
#define PRIO1   __builtin_amdgcn_s_setprio(1)
#define PRIO0   __builtin_amdgcn_s_setprio(0)

// Swizzled LDS read of one bf16x8 fragment from a [128][64]bf16 half-tile.
// Logical byte lb = row*128 + kstep*64 + kblk*16 ; stored at lb ^ ((row&7)<<4).
__device__ __forceinline__ bf16x8 ldsFrag(const short* base, int rowInHalf,
                                          int kstep, int kblk) {
  const int lb = rowInHalf * 128 + kstep * 64 + kblk * 16;
  const int addr = lb ^ ((rowInHalf & 7) << 4);
  return *(const bf16x8*)((const char*)base + addr);
}

// ---------------------------------------------------------------------------
// Deep-pipelined 256x256 GEMM core. A[M,K] row-major, B[N,K] row-major (B^T).
// K multiple of 128. 512 threads (8 waves, 2Mx4N).
// LDS: 8 half-buffers of 16 KB = 128 KB; half-tile = [128 rows][64 cols] bf16.
// Per K-tile (4 phases q0..q3), quadrant (mh,nh) computed per phase in order
// (0,0),(0,1),(1,1),(1,0). Reads per phase touch one contiguous 64-row range
// per half; staging of kt+2's 64-row units goes into the ranges freed by the
// immediately preceding phase (barrier-separated). vmcnt(8) once per K-tile.
// ---------------------------------------------------------------------------
__device__ __forceinline__ void gemm256(const short* __restrict__ A, int lda, int aRow,
                                        const short* __restrict__ B, int ldb, int bRow,
                                        int K, short* lds, f32x4 (&acc)[8][4]) {
  const int tid  = threadIdx.x;
  const int w    = tid >> 6, l = tid & 63;
  const int wr   = w >> 2, wc = w & 3;             // 2 x 4 wave grid
  const int lrow = l & 15, kblk = l >> 4;
  const int sr   = w * 8 + (l >> 3);               // stage row in 64-row unit
  const int sc   = 8 * ((l & 7) ^ ((l >> 3) & 7)); // pre-swizzled col (elems)
  const int nkt  = K >> 6;                         // number of 64-wide K-tiles

#define HB(d, mat, half) (lds + (((d) * 2 + (mat)) * 2 + (half)) * 8192)

// Stage one 64-row x 64-col unit (8 KB): rows [rq*64, rq*64+64) of half.
#define STAGE1(d, mat, half, rq, gptr, ldg, rowB, kt) do {                     \
    const int ktc = ((kt) < nkt) ? (kt) : (nkt - 1);                           \
    const short* _g = (gptr) + (size_t)((rowB) + (half) * 128 + (rq) * 64 + sr)\
                               * (ldg) + (ktc * 64 + sc);                      \
    gload_lds16(_g, HB(d, mat, half) + (rq) * 4096 + w * 512);                 \
  } while (0)

#define READ_A(d, mh) do {                                                     \
    const short* _ab = HB(d, 0, wr);                                           \
    _Pragma("unroll") for (int i = 0; i < 4; ++i)                              \
      _Pragma("unroll") for (int ks = 0; ks < 2; ++ks)                         \
        aF[i][ks] = ldsFrag(_ab, (mh) * 64 + i * 16 + lrow, ks, kblk);         \
  } while (0)

// B frag rows: nh*64 + (wc&1)*32 + u*16 + lrow  (phase nh reads rows nh*64+[0,64))
#define READ_B(d, nh, arr) do {                                                \
    const short* _bb = HB(d, 1, (wc >> 1));                                    \
    _Pragma("unroll") for (int u = 0; u < 2; ++u)                              \
      _Pragma("unroll") for (int ks = 0; ks < 2; ++ks)                         \
        arr[u][ks] = ldsFrag(_bb, (nh) * 64 + (wc & 1) * 32 + u * 16 + lrow,   \
                             ks, kblk);                                        \
  } while (0)

#define MFMA16(mh, nh, arr) do {                                               \
    _Pragma("unroll") for (int i = 0; i < 4; ++i)                              \
      _Pragma("unroll") for (int u = 0; u < 2; ++u)                            \
        _Pragma("unroll") for (int ks = 0; ks < 2; ++ks)                       \
          acc[(mh) * 4 + i][(nh) * 2 + u] =                                    \
            mfmaOp(aF[i][ks], arr[u][ks], acc[(mh) * 4 + i][(nh) * 2 + u]);    \
  } while (0)

// One K-tile kt in dbuf d; stages kt+2's 8 units into freed regions of d.
#define KTILE(d, kt) do {                                                      \
    /* q0: quad(0,0) -- reads A rows[0,64), B rows[0,64) of both halves */     \
    READ_A(d, 0); READ_B(d, 0, bN0);                                           \
    BARRIER; LGKM0; PRIO1; MFMA16(0, 0, bN0); PRIO0; BARRIER;                  \
    /* q1: quad(0,1) -- reads B rows[64,128); stage A r0 units of kt+2 */      \
    READ_B(d, 1, bN1);                                                         \
    STAGE1(d, 0, 0, 0, A, lda, aRow, (kt) + 2);                                \
    STAGE1(d, 0, 1, 0, A, lda, aRow, (kt) + 2);                                \
    BARRIER; LGKM0; PRIO1; MFMA16(0, 1, bN1); PRIO0; BARRIER;                  \
    /* q2: quad(1,1) -- reads A rows[64,128); stage B r0 units of kt+2 */      \
    READ_A(d, 1);                                                              \
    STAGE1(d, 1, 0, 0, B, ldb, bRow, (kt) + 2);                                \
    STAGE1(d, 1, 1, 0, B, ldb, bRow, (kt) + 2);                                \
    BARRIER; LGKM0; PRIO1; MFMA16(1, 1, bN1); PRIO0; BARRIER;                  \
    /* q3: quad(1,0) -- no ds_reads; stage A r1 + B r1 units of kt+2 */        \
    STAGE1(d, 0, 0, 1, A, lda, aRow, (kt) + 2);                                \
    STAGE1(d, 0, 1, 1, A, lda, aRow, (kt) + 2);                                \
    STAGE1(d, 1, 0, 1, B, ldb, bRow, (kt) + 2);                                \
    STAGE1(d, 1, 1, 1, B, ldb, bRow, (kt) + 2);                                \
    BARRIER; PRIO1; MFMA16(1, 0, bN0); PRIO0; VMCNT8; BARRIER;                 \
  } while (0)

  // ---- prologue: stage kt0 (dbuf0) then kt1 (dbuf1), 8 units each ---------
#pragma unroll
  for (int rq = 0; rq < 2; ++rq) {
    STAGE1(0, 0, 0, rq, A, lda, aRow, 0); STAGE1(0, 0, 1, rq, A, lda, aRow, 0);
    STAGE1(0, 1, 0, rq, B, ldb, bRow, 0); STAGE1(0, 1, 1, rq, B, ldb, bRow, 0);
  }
#pragma unroll
  for (int rq = 0; rq < 2; ++rq) {
    STAGE1(1, 0, 0, rq, A, lda, aRow, 1); STAGE1(1, 0, 1, rq, A, lda, aRow, 1);
    STAGE1(1, 1, 0, rq, B, ldb, bRow, 1); STAGE1(1, 1, 1, rq, B, ldb, bRow, 1);
  }
  VMCNT8;                            // kt0 landed; kt1's 8 units in flight
  BARRIER;

  bf16x8 aF[4][2], bN0[2][2], bN1[2][2];

  for (int kt = 0; kt < nkt; kt += 2) {
    KTILE(0, kt);
    KTILE(1, kt + 1);
  }
#undef HB
#undef STAGE1
#undef READ_A
#undef READ_B
#undef MFMA16
#undef KTILE
}

#define GEMM_SHARED __shared__ __align__(16) short lds[65536];

// Epilogue index helpers. acc[m][n]:
//   row = blockM + wr*128 + m*16 + kblk*4 + j
//   col = blockN + (wc>>1)*128 + (n>>1)*64 + (wc&1)*32 + (n&1)*16 + lrow
#define EPILOG_VARS                                        \
  const int lane = threadIdx.x & 63;                       \
  const int w    = threadIdx.x >> 6;                       \
  const int wr = w >> 2, wc = w & 3;                       \
  const int lrow = lane & 15, kblk = lane >> 4;            \
  const int colBase = (wc >> 1) * 128 + (wc & 1) * 32 + lrow;
#define COL_OF(n) (colBase + ((n) >> 1) * 64 + ((n) & 1) * 16)

// ---- fused QKV projection: N = 6144 (Q | K | V segments) ------------------
__global__ __launch_bounds__(512, 1) void k_proj_qkv(const short* __restrict__ X,
                                                     const short* __restrict__ WT,
                                                     const float* __restrict__ bq,
                                                     const float* __restrict__ bk,
                                                     const float* __restrict__ bv,
                                                     short* __restrict__ Qm,
                                                     short* __restrict__ Km,
                                                     short* __restrict__ vT) {
  GEMM_SHARED
  f32x4 acc[8][4];
#pragma unroll
  for (int m = 0; m < 8; ++m)
#pragma unroll
    for (int n = 0; n < 4; ++n) acc[m][n] = (f32x4){0.f, 0.f, 0.f, 0.f};
  const int blockM = blockIdx.y * 256;
  const int blockN = blockIdx.x * 256;     // [0, 6144), never straddles segs
  gemm256(X, D_MODEL, blockM, WT, D_MODEL, blockN, D_MODEL, lds, acc);
  EPILOG_VARS
  const int seg = blockN >> 11;            // 0=Q 1=K 2=V
  const float* bias = (seg == 0) ? bq : (seg == 1) ? bk : bv;
#pragma unroll
  for (int m = 0; m < 8; ++m)
#pragma unroll
    for (int n = 0; n < 4; ++n) {
      const int gcol = blockN + COL_OF(n);
      const int e = gcol & 2047;
      const float bvv = bias[e];
#pragma unroll
      for (int j = 0; j < 4; ++j) {
        const int row = blockM + wr * 128 + m * 16 + kblk * 4 + j;
        float v = acc[m][n][j] + bvv;
        if (seg < 2) {
          v = (v > 0.f) ? (v + 1.f) : __expf(v);      // elu(x)+1
          (seg == 0 ? Qm : Km)[(size_t)row * D_INNER + e] = f2bf(v);
        } else {
          const int b = row >> 11, mm = row & 2047;
          vT[((size_t)b * D_INNER + e) * SEQ + mm] = f2bf(v);
        }
      }
    }
}

// ---- scores = tril(Q K^T), bf16; dense triangular 256-tile grid -----------
__global__ __launch_bounds__(512, 1) void k_qkt(const short* __restrict__ Q,
                                                const short* __restrict__ Kmat,
                                                short* __restrict__ S) {
  const int b = blockIdx.y;
  const int t = blockIdx.x;                // 0..35 -> (ib, jb<=ib), 8x8 tiles
  int ib = (int)((-1.0f + sqrtf(8.0f * (float)t + 1.0f)) * 0.5f);
  while ((ib + 1) * (ib + 2) / 2 <= t) ++ib;
  while (ib * (ib + 1) / 2 > t) --ib;
  const int jb = t - ib * (ib + 1) / 2;
  GEMM_SHARED
  f32x4 acc[8][4];
#pragma unroll
  for (int m = 0; m < 8; ++m)
#pragma unroll
    for (int n = 0; n < 4; ++n) acc[m][n] = (f32x4){0.f, 0.f, 0.f, 0.f};
  short* Sb = S + (size_t)b * SEQ * SEQ;
  gemm256(Q + (size_t)b * SEQ * D_INNER, D_INNER, ib * 256,
          Kmat + (size_t)b * SEQ * D_INNER, D_INNER, jb * 256,
          D_INNER, lds, acc);
  EPILOG_VARS
  const bool diag = (jb == ib);
#pragma unroll
  for (int m = 0; m < 8; ++m)
#pragma unroll
    for (int n = 0; n < 4; ++n) {
      const int col = jb * 256 + COL_OF(n);                     // j
#pragma unroll
      for (int j = 0; j < 4; ++j) {
        const int row = ib * 256 + wr * 128 + m * 16 + kblk * 4 + j;  // i
        float v = acc[m][n][j];
        if (diag && col > row) v = 0.f;
        Sb[(size_t)row * SEQ + col] = f2bf(v);
      }
    }
}

// ---- denominator: rowsum of valid (256-block prefix) scores + eps ---------
__global__ __launch_bounds__(256) void k_denom(const short* __restrict__ S,
                                               float* __restrict__ denom) {
  const int grow = blockIdx.x;                 // 0..8191
  const int b = grow >> 11, i = grow & 2047;
  const int limit = ((i >> 8) + 1) << 8;       // cols valid: [0, limit)
  const short* r = S + ((size_t)b * SEQ + i) * SEQ;
  const int tid = threadIdx.x;
  float s = 0.f;
  if (tid * 8 < limit) {
    short8v v = *(const short8v*)(r + tid * 8);
#pragma unroll
    for (int t = 0; t < 8; ++t) s += bf2f(v[t]);
  }
#pragma unroll
  for (int off = 32; off >= 1; off >>= 1) s += __shfl_down(s, off, 64);
  __shared__ float ws[4];
  if ((tid & 63) == 0) ws[tid >> 6] = s;
  __syncthreads();
  if (tid == 0) denom[grow] = ws[0] + ws[1] + ws[2] + ws[3] + 1e-6f;
}

// ---- attn = (S V) / denom, bf16; K truncated; heavy (large ib) first ------
__global__ __launch_bounds__(512, 1) void k_av(const short* __restrict__ S,
                                               const short* __restrict__ VT,
                                               const float* __restrict__ denom,
                                               short* __restrict__ attn) {
  const int b = blockIdx.z;
  const int ib = 7 - blockIdx.y;           // heavy blocks dispatched first
  const int eb = blockIdx.x;
  GEMM_SHARED
  f32x4 acc[8][4];
#pragma unroll
  for (int m = 0; m < 8; ++m)
#pragma unroll
    for (int n = 0; n < 4; ++n) acc[m][n] = (f32x4){0.f, 0.f, 0.f, 0.f};
  gemm256(S + (size_t)b * SEQ * SEQ, SEQ, ib * 256,
          VT + (size_t)b * (size_t)D_INNER * SEQ, SEQ, eb * 256,
          (ib + 1) * 256, lds, acc);
  EPILOG_VARS
#pragma unroll
  for (int m = 0; m < 8; ++m)
#pragma unroll
    for (int j = 0; j < 4; ++j) {
      const int row = ib * 256 + wr * 128 + m * 16 + kblk * 4 + j;  // token
      const float rcp = 1.0f / denom[b * SEQ + row];
#pragma unroll
      for (int n = 0; n < 4; ++n) {
        const int col = eb * 256 + COL_OF(n);                       // e
        attn[((size_t)(b * SEQ + row)) * D_INNER + col] = f2bf(acc[m][n][j] * rcp);
      }
    }
}

// ---- final: out = attn Wo + bo (fp32 out) ---------------------------------
__global__ __launch_bounds__(512, 1) void k_out(const short* __restrict__ A,
                                                const short* __restrict__ WoT,
                                                const float* __restrict__ bo,
                                                float* __restrict__ out) {
  GEMM_SHARED
  f32x4 acc[8][4];
#pragma unroll
  for (int m = 0; m < 8; ++m)
#pragma unroll
    for (int n = 0; n < 4; ++n) acc[m][n] = (f32x4){0.f, 0.f, 0.f, 0.f};
  const int blockM = blockIdx.y * 256;
  const int blockN = blockIdx.x * 256;     // [0, 1024)
  gemm256(A, D_INNER, blockM, WoT, D_INNER, blockN, D_INNER, lds, acc);
  EPILOG_VARS
#pragma unroll
  for (int m = 0; m < 8; ++m)
#pragma unroll
    for (int n = 0; n < 4; ++n) {
      const int col = blockN + COL_OF(n);
      const float bvv = bo[col];
#pragma unroll
      for (int j = 0; j < 4; ++j) {
        const int row = blockM + wr * 128 + m * 16 + kblk * 4 + j;
        out[(size_t)row * D_MODEL + col] = acc[m][n][j] + bvv;
      }
    }
}

// ---- converts -------------------------------------------------------------
__global__ void k_cvt(const float* __restrict__ in, short* __restrict__ out, int n4) {
  int i = blockIdx.x * blockDim.x + threadIdx.x;
  const int stride = gridDim.x * blockDim.x;
  for (; i < n4; i += stride) {
    float4 v = ((const float4*)in)[i];
    short4 o;
    o.x = f2bf(v.x); o.y = f2bf(v.y); o.z = f2bf(v.z); o.w = f2bf(v.w);
    ((short4*)out)[i] = o;
  }
}

// coalesced tiled transpose: in [R][C] fp32 -> out [C][R] bf16
__global__ __launch_bounds__(256) void k_transpose2(const float* __restrict__ in,
                                                    short* __restrict__ out,
                                                    int R, int C) {
  __shared__ float t[32][33];
  const int c0 = blockIdx.x * 32, r0 = blockIdx.y * 32;
  const int tx = threadIdx.x & 31, ty = (threadIdx.x >> 5) * 4;
#pragma unroll
  for (int i = 0; i < 4; ++i)
    t[ty + i][tx] = in[(size_t)(r0 + ty + i) * C + (c0 + tx)];
  __syncthreads();
#pragma unroll
  for (int i = 0; i < 4; ++i)
    out[(size_t)(c0 + ty + i) * R + (r0 + tx)] = f2bf(t[tx][ty + i]);
}

// ---------------------------------------------------------------------------
extern "C" void kernel_launch(void* const* d_in, const int* in_sizes, int n_in,
                              void* d_out, int out_size, void* d_ws, size_t ws_size,
                              hipStream_t stream) {
  const float* x  = (const float*)d_in[0];
  const float* Wq = (const float*)d_in[1];
  const float* bq = (const float*)d_in[2];
  const float* Wk = (const float*)d_in[3];
  const float* bk = (const float*)d_in[4];
  const float* Wv = (const float*)d_in[5];
  const float* bv = (const float*)d_in[6];
  const float* Wo = (const float*)d_in[7];
  const float* bo = (const float*)d_in[8];
  float* out = (float*)d_out;

  // workspace layout (bf16 shorts unless noted); total ~201.4 MB
  short* xb    = (short*)d_ws;                          // [8192][1024]
  short* wqkvT = xb    + (size_t)MTOT * D_MODEL;        // [6144][1024] (Q|K|V)
  short* woT   = wqkvT + (size_t)3 * D_INNER * D_MODEL; // [1024][2048]
  short* Qm    = woT   + (size_t)D_MODEL * D_INNER;     // [8192][2048]
  short* Km    = Qm    + (size_t)MTOT * D_INNER;
  short* vT    = Km    + (size_t)MTOT * D_INNER;        // [4][2048 e][2048 m]
  short* Sc    = vT    + (size_t)MTOT * D_INNER;        // [4][2048][2048]
  short* attn  = Sc    + (size_t)NBATCH * SEQ * SEQ;    // [8192][2048]
  float* den   = (float*)(attn + (size_t)MTOT * D_INNER);  // [8192]

  dim3 b256(256), b512(512);
  k_cvt<<<2048, b256, 0, stream>>>(x, xb, MTOT * D_MODEL / 4);
  // W[1024][2048] -> WT[2048][1024]
  k_transpose2<<<dim3(64, 32), b256, 0, stream>>>(Wq, wqkvT, 1024, 2048);
  k_transpose2<<<dim3(64, 32), b256, 0, stream>>>(Wk, wqkvT + (size_t)D_INNER * D_MODEL, 1024, 2048);
  k_transpose2<<<dim3(64, 32), b256, 0, stream>>>(Wv, wqkvT + (size_t)2 * D_INNER * D_MODEL, 1024, 2048);
  // Wo[2048][1024] -> WoT[1024][2048]
  k_transpose2<<<dim3(32, 64), b256, 0, stream>>>(Wo, woT, 2048, 1024);

  k_proj_qkv<<<dim3(24, 32), b512, 0, stream>>>(xb, wqkvT, bq, bk, bv, Qm, Km, vT);

  k_qkt<<<dim3(36, NBATCH), b512, 0, stream>>>(Qm, Km, Sc);
  k_denom<<<MTOT, b256, 0, stream>>>(Sc, den);
  k_av<<<dim3(8, 8, NBATCH), b512, 0, stream>>>(Sc, vT, den, attn);
  k_out<<<dim3(4, 32), b512, 0, stream>>>(attn, woT, bo, out);
}

// Round 5
// 387.694 us; speedup vs baseline: 1.1222x; 1.1222x over previous
//
#include <hip/hip_runtime.h>
#include <hip/hip_bf16.h>

// ---------------------------------------------------------------------------
// LinearAttentionBlock: Q=phi(xWq+bq), K=phi(xWk+bk), V=xWv+bv
// scores = tril(Q K^T); out = ((scores V) / (rowsum(scores)+eps)) Wo + bo
// GEMM core: 2-phase double-buffered 128x128 tile, BK=32, 4 waves (r2 base)
//  + LDS 4-slot XOR swizzle (both-sides-consistent)  [bank conflict fix]
//  + bijective XCD-aware grid swizzle (T1).
// ---------------------------------------------------------------------------

#define D_MODEL 1024
#define D_INNER 2048
#define SEQ     2048
#define NBATCH  4
#define MTOT    (NBATCH * SEQ)   // 8192

typedef __attribute__((ext_vector_type(8))) __bf16 bf16x8;
typedef __attribute__((ext_vector_type(4))) float  f32x4;
typedef __attribute__((ext_vector_type(8))) short  short8v;

__device__ __forceinline__ short f2bf(float f) {      // RNE f32 -> bf16 bits
  union { float f; unsigned u; } x; x.f = f;
  unsigned r = x.u + 0x7fffu + ((x.u >> 16) & 1u);
  return (short)(r >> 16);
}
__device__ __forceinline__ float bf2f(short s) {
  union { unsigned u; float f; } x; x.u = ((unsigned)(unsigned short)s) << 16;
  return x.f;
}

typedef const void __attribute__((address_space(1)))* as1cv;
typedef void __attribute__((address_space(3)))* as3v;

__device__ __forceinline__ void gload_lds16(const void* g, void* l) {
  __builtin_amdgcn_global_load_lds((as1cv)g, (as3v)l, 16, 0, 0);
}

__device__ __forceinline__ f32x4 mfma16(bf16x8 a, bf16x8 b, f32x4 c) {
  return __builtin_amdgcn_mfma_f32_16x16x32_bf16(a, b, c, 0, 0, 0);
}

// XCD-aware bijective grid swizzle; all our grid x-dims are divisible by 8.
// Consecutive dispatch ids round-robin XCDs; remap so each XCD owns a
// contiguous chunk of tile space (L2 locality).
__device__ __forceinline__ int xcd_swz(int orig, int n) {
  return (orig & 7) * (n >> 3) + (orig >> 3);
}

// ---------------------------------------------------------------------------
// LDS tile: [128 rows][32 cols] bf16, 64 B rows, 4 x 16B slots per row.
// Swizzle: slot ^= (row>>1)&3  (involution). Reads 2-way-bank-aliased = free.
// ---------------------------------------------------------------------------
__device__ __forceinline__ bf16x8 ldsFrag(const short* base, int row, int kblk) {
  const int lb = row * 64 + kblk * 16;
  const int addr = lb ^ (((row >> 1) & 3) << 4);
  return *(const bf16x8*)((const char*)base + addr);
}

// Stage one 128x32 bf16 tile (8 KB) from row-major global [ldg] into LDS.
// 256 threads x 2 global_load_lds(16B). Linear LDS dest (wave-uniform base +
// lane*16); swizzle realized by pre-swizzling the per-lane GLOBAL source col.
__device__ __forceinline__ void stage_tile(const short* __restrict__ g, int ldg,
                                           int rowBase, int k0,
                                           short* lds) {
  const int t  = threadIdx.x;                       // 0..255
  const int r0 = t >> 2;                            // rows 0..63 (+64 for 2nd)
  const int sc = (((t & 3) ^ ((t >> 3) & 3))) * 8;  // pre-swizzled col (elems)
  const short* s0 = g + (size_t)(rowBase + r0) * ldg + (k0 + sc);
  gload_lds16(s0, lds + t * 8);                           // rows 0..63
  gload_lds16(s0 + (size_t)64 * ldg, lds + t * 8 + 2048); // rows 64..127
}

// One BK=32 K-step: 8 x ds_read_b128 + 16 x MFMA from a staged 128x32 pair.
__device__ __forceinline__ void compute_step(const short* __restrict__ As,
                                             const short* __restrict__ Bs,
                                             f32x4 acc[4][4],
                                             int wr, int wc, int lrow, int kblk) {
  bf16x8 a[4], b[4];
#pragma unroll
  for (int m = 0; m < 4; ++m)
    a[m] = ldsFrag(As, wr * 64 + m * 16 + lrow, kblk);
#pragma unroll
  for (int n = 0; n < 4; ++n)
    b[n] = ldsFrag(Bs, wc * 64 + n * 16 + lrow, kblk);
#pragma unroll
  for (int m = 0; m < 4; ++m)
#pragma unroll
    for (int n = 0; n < 4; ++n)
      acc[m][n] = mfma16(a[m], b[n], acc[m][n]);
}

// A[M,K] row-major, B stored transposed [N,K] row-major. acc += A * B^T.
// (k1-k0) must be a positive multiple of 64. 2-phase double-buffered.
__device__ __forceinline__ void gemm_pipe(const short* __restrict__ A, int lda, int aRowBase,
                                          const short* __restrict__ B, int ldb, int bRowBase,
                                          int k0, int k1,
                                          short* As0, short* Bs0, short* As1, short* Bs1,
                                          f32x4 acc[4][4]) {
  const int lane = threadIdx.x & 63;
  const int wid  = threadIdx.x >> 6;
  const int wr = wid >> 1, wc = wid & 1;
  const int lrow = lane & 15, kblk = lane >> 4;
  stage_tile(A, lda, aRowBase, k0, As0);
  stage_tile(B, ldb, bRowBase, k0, Bs0);
  __syncthreads();
  for (int k = k0; k < k1; k += 64) {
    if (k + 32 < k1) {                       // prefetch k+32 into buf1
      stage_tile(A, lda, aRowBase, k + 32, As1);
      stage_tile(B, ldb, bRowBase, k + 32, Bs1);
    }
    compute_step(As0, Bs0, acc, wr, wc, lrow, kblk);
    __syncthreads();
    if (k + 64 < k1) {                       // prefetch k+64 into buf0
      stage_tile(A, lda, aRowBase, k + 64, As0);
      stage_tile(B, ldb, bRowBase, k + 64, Bs0);
    }
    compute_step(As1, Bs1, acc, wr, wc, lrow, kblk);
    __syncthreads();
  }
}

#define GEMM_PRE                                           \
  __shared__ __align__(16) short As0[128 * 32], Bs0[128 * 32];  \
  __shared__ __align__(16) short As1[128 * 32], Bs1[128 * 32];  \
  f32x4 acc[4][4];                                         \
  _Pragma("unroll")                                        \
  for (int m = 0; m < 4; ++m)                              \
    _Pragma("unroll")                                      \
    for (int n = 0; n < 4; ++n) acc[m][n] = (f32x4){0.f, 0.f, 0.f, 0.f};

#define EPILOG_VARS                                        \
  const int lane = threadIdx.x & 63;                       \
  const int wid  = threadIdx.x >> 6;                       \
  const int wr = wid >> 1, wc = wid & 1;                   \
  const int lrow = lane & 15, kblk = lane >> 4;

// ---- fused QKV projection: N = 6144 (Q | K | V segments) ------------------
__global__ __launch_bounds__(256) void k_proj_qkv(const short* __restrict__ X,
                                                  const short* __restrict__ WT,
                                                  const float* __restrict__ bq,
                                                  const float* __restrict__ bk,
                                                  const float* __restrict__ bv,
                                                  short* __restrict__ Qm,
                                                  short* __restrict__ Km,
                                                  short* __restrict__ vT) {
  GEMM_PRE
  const int tile = xcd_swz(blockIdx.x, 3072);   // 64 M-tiles x 48 N-tiles
  const int blockM = (tile / 48) * 128;
  const int blockN = (tile % 48) * 128;         // [0, 6144)
  gemm_pipe(X, D_MODEL, blockM, WT, D_MODEL, blockN, 0, D_MODEL,
            As0, Bs0, As1, Bs1, acc);
  EPILOG_VARS
  const int seg = blockN >> 11;            // 0=Q 1=K 2=V
  const float* bias = (seg == 0) ? bq : (seg == 1) ? bk : bv;
#pragma unroll
  for (int m = 0; m < 4; ++m)
#pragma unroll
    for (int n = 0; n < 4; ++n) {
      const int gcol = blockN + wc * 64 + n * 16 + lrow;
      const int e = gcol & 2047;
      const float bvv = bias[e];
#pragma unroll
      for (int j = 0; j < 4; ++j) {
        const int row = blockM + wr * 64 + m * 16 + kblk * 4 + j;  // token
        float v = acc[m][n][j] + bvv;
        if (seg < 2) {
          v = (v > 0.f) ? (v + 1.f) : __expf(v);      // elu(x)+1
          (seg == 0 ? Qm : Km)[(size_t)row * D_INNER + e] = f2bf(v);
        } else {
          const int b = row >> 11, mm = row & 2047;
          vT[((size_t)b * D_INNER + e) * SEQ + mm] = f2bf(v);
        }
      }
    }
}

// ---- scores = tril(Q K^T), bf16; dense triangular grid (no zero-fill) -----
__global__ __launch_bounds__(256) void k_qkt(const short* __restrict__ Q,
                                             const short* __restrict__ Kmat,
                                             short* __restrict__ S) {
  const int b = blockIdx.y;
  const int t = xcd_swz(blockIdx.x, 136);  // 0..135 -> (ib, jb<=ib)
  int ib = (int)((-1.0f + sqrtf(8.0f * (float)t + 1.0f)) * 0.5f);
  while ((ib + 1) * (ib + 2) / 2 <= t) ++ib;
  while (ib * (ib + 1) / 2 > t) --ib;
  const int jb = t - ib * (ib + 1) / 2;
  GEMM_PRE
  short* Sb = S + (size_t)b * SEQ * SEQ;
  gemm_pipe(Q + (size_t)b * SEQ * D_INNER, D_INNER, ib * 128,
            Kmat + (size_t)b * SEQ * D_INNER, D_INNER, jb * 128,
            0, D_INNER, As0, Bs0, As1, Bs1, acc);
  EPILOG_VARS
  const bool diag = (jb == ib);
#pragma unroll
  for (int m = 0; m < 4; ++m)
#pragma unroll
    for (int n = 0; n < 4; ++n) {
      const int col = jb * 128 + wc * 64 + n * 16 + lrow;       // j
#pragma unroll
      for (int j = 0; j < 4; ++j) {
        const int row = ib * 128 + wr * 64 + m * 16 + kblk * 4 + j;  // i
        float v = acc[m][n][j];
        if (diag && col > row) v = 0.f;
        Sb[(size_t)row * SEQ + col] = f2bf(v);
      }
    }
}

// ---- denominator: rowsum of valid (128-block prefix) scores + eps ---------
__global__ __launch_bounds__(256) void k_denom(const short* __restrict__ S,
                                               float* __restrict__ denom) {
  const int grow = blockIdx.x;                 // 0..8191
  const int b = grow >> 11, i = grow & 2047;
  const int limit = ((i >> 7) + 1) << 7;       // cols valid: [0, limit)
  const short* r = S + ((size_t)b * SEQ + i) * SEQ;
  const int tid = threadIdx.x;
  float s = 0.f;
  if (tid * 8 < limit) {
    short8v v = *(const short8v*)(r + tid * 8);
#pragma unroll
    for (int t = 0; t < 8; ++t) s += bf2f(v[t]);
  }
#pragma unroll
  for (int off = 32; off >= 1; off >>= 1) s += __shfl_down(s, off, 64);
  __shared__ float ws[4];
  if ((tid & 63) == 0) ws[tid >> 6] = s;
  __syncthreads();
  if (tid == 0) denom[grow] = ws[0] + ws[1] + ws[2] + ws[3] + 1e-6f;
}

// ---- attn = (S V) / denom, bf16; K truncated; heavy (large ib) first ------
__global__ __launch_bounds__(256) void k_av(const short* __restrict__ S,
                                            const short* __restrict__ VT,
                                            const float* __restrict__ denom,
                                            short* __restrict__ attn) {
  const int b = blockIdx.y;
  const int tile = xcd_swz(blockIdx.x, 256);
  const int ib = 15 - (tile >> 4);         // heavy blocks dispatched first
  const int eb = tile & 15;
  GEMM_PRE
  gemm_pipe(S + (size_t)b * SEQ * SEQ, SEQ, ib * 128,
            VT + (size_t)b * (size_t)D_INNER * SEQ, SEQ, eb * 128,
            0, (ib + 1) * 128, As0, Bs0, As1, Bs1, acc);
  EPILOG_VARS
  const int blockM = ib * 128;
#pragma unroll
  for (int m = 0; m < 4; ++m)
#pragma unroll
    for (int j = 0; j < 4; ++j) {
      const int row = blockM + wr * 64 + m * 16 + kblk * 4 + j;  // token
      const float rcp = 1.0f / denom[b * SEQ + row];
#pragma unroll
      for (int n = 0; n < 4; ++n) {
        const int col = eb * 128 + wc * 64 + n * 16 + lrow;      // e
        attn[((size_t)(b * SEQ + row)) * D_INNER + col] = f2bf(acc[m][n][j] * rcp);
      }
    }
}

// ---- final: out = attn Wo + bo (fp32 out) ---------------------------------
__global__ __launch_bounds__(256) void k_out(const short* __restrict__ A,
                                             const short* __restrict__ WoT,
                                             const float* __restrict__ bo,
                                             float* __restrict__ out) {
  GEMM_PRE
  const int tile = xcd_swz(blockIdx.x, 512);   // 64 M-tiles x 8 N-tiles
  const int blockM = (tile >> 3) * 128;
  const int blockN = (tile & 7) * 128;
  gemm_pipe(A, D_INNER, blockM, WoT, D_INNER, blockN, 0, D_INNER,
            As0, Bs0, As1, Bs1, acc);
  EPILOG_VARS
#pragma unroll
  for (int m = 0; m < 4; ++m)
#pragma unroll
    for (int n = 0; n < 4; ++n) {
      const int col = blockN + wc * 64 + n * 16 + lrow;
      const float bvv = bo[col];
#pragma unroll
      for (int j = 0; j < 4; ++j) {
        const int row = blockM + wr * 64 + m * 16 + kblk * 4 + j;
        out[(size_t)row * D_MODEL + col] = acc[m][n][j] + bvv;
      }
    }
}

// ---- converts -------------------------------------------------------------
__global__ void k_cvt(const float* __restrict__ in, short* __restrict__ out, int n4) {
  int i = blockIdx.x * blockDim.x + threadIdx.x;
  const int stride = gridDim.x * blockDim.x;
  for (; i < n4; i += stride) {
    float4 v = ((const float4*)in)[i];
    short4 o;
    o.x = f2bf(v.x); o.y = f2bf(v.y); o.z = f2bf(v.z); o.w = f2bf(v.w);
    ((short4*)out)[i] = o;
  }
}

// coalesced tiled transpose: in [R][C] fp32 -> out [C][R] bf16
// blockIdx.z selects among 3 equal-shaped weight matrices (Wq,Wk,Wv).
__global__ __launch_bounds__(256) void k_transpose3(const float* __restrict__ w0,
                                                    const float* __restrict__ w1,
                                                    const float* __restrict__ w2,
                                                    short* __restrict__ out,
                                                    int R, int C) {
  __shared__ float t[32][33];
  const float* in = (blockIdx.z == 0) ? w0 : (blockIdx.z == 1) ? w1 : w2;
  short* o = out + (size_t)blockIdx.z * R * C;
  const int c0 = blockIdx.x * 32, r0 = blockIdx.y * 32;
  const int tx = threadIdx.x & 31, ty = (threadIdx.x >> 5) * 4;
#pragma unroll
  for (int i = 0; i < 4; ++i)
    t[ty + i][tx] = in[(size_t)(r0 + ty + i) * C + (c0 + tx)];
  __syncthreads();
#pragma unroll
  for (int i = 0; i < 4; ++i)
    o[(size_t)(c0 + ty + i) * R + (r0 + tx)] = f2bf(t[tx][ty + i]);
}

__global__ __launch_bounds__(256) void k_transpose1(const float* __restrict__ in,
                                                    short* __restrict__ out,
                                                    int R, int C) {
  __shared__ float t[32][33];
  const int c0 = blockIdx.x * 32, r0 = blockIdx.y * 32;
  const int tx = threadIdx.x & 31, ty = (threadIdx.x >> 5) * 4;
#pragma unroll
  for (int i = 0; i < 4; ++i)
    t[ty + i][tx] = in[(size_t)(r0 + ty + i) * C + (c0 + tx)];
  __syncthreads();
#pragma unroll
  for (int i = 0; i < 4; ++i)
    out[(size_t)(c0 + ty + i) * R + (r0 + tx)] = f2bf(t[tx][ty + i]);
}

// ---------------------------------------------------------------------------
extern "C" void kernel_launch(void* const* d_in, const int* in_sizes, int n_in,
                              void* d_out, int out_size, void* d_ws, size_t ws_size,
                              hipStream_t stream) {
  const float* x  = (const float*)d_in[0];
  const float* Wq = (const float*)d_in[1];
  const float* bq = (const float*)d_in[2];
  const float* Wk = (const float*)d_in[3];
  const float* bk = (const float*)d_in[4];
  const float* Wv = (const float*)d_in[5];
  const float* bv = (const float*)d_in[6];
  const float* Wo = (const float*)d_in[7];
  const float* bo = (const float*)d_in[8];
  float* out = (float*)d_out;

  // workspace layout (bf16 shorts unless noted); total ~201.4 MB
  short* xb    = (short*)d_ws;                          // [8192][1024]
  short* wqkvT = xb    + (size_t)MTOT * D_MODEL;        // [6144][1024] (Q|K|V)
  short* woT   = wqkvT + (size_t)3 * D_INNER * D_MODEL; // [1024][2048]
  short* Qm    = woT   + (size_t)D_MODEL * D_INNER;     // [8192][2048]
  short* Km    = Qm    + (size_t)MTOT * D_INNER;
  short* vT    = Km    + (size_t)MTOT * D_INNER;        // [4][2048 e][2048 m]
  short* Sc    = vT    + (size_t)MTOT * D_INNER;        // [4][2048][2048]
  short* attn  = Sc    + (size_t)NBATCH * SEQ * SEQ;    // [8192][2048]
  float* den   = (float*)(attn + (size_t)MTOT * D_INNER);  // [8192]

  dim3 b256(256);
  k_cvt<<<2048, b256, 0, stream>>>(x, xb, MTOT * D_MODEL / 4);
  // W[1024][2048] -> WT[2048][1024] x3 (Q,K,V) in one launch
  k_transpose3<<<dim3(64, 32, 3), b256, 0, stream>>>(Wq, Wk, Wv, wqkvT, 1024, 2048);
  // Wo[2048][1024] -> WoT[1024][2048]
  k_transpose1<<<dim3(32, 64), b256, 0, stream>>>(Wo, woT, 2048, 1024);

  k_proj_qkv<<<3072, b256, 0, stream>>>(xb, wqkvT, bq, bk, bv, Qm, Km, vT);

  k_qkt<<<dim3(136, NBATCH), b256, 0, stream>>>(Qm, Km, Sc);
  k_denom<<<MTOT, b256, 0, stream>>>(Sc, den);
  k_av<<<dim3(256, NBATCH), b256, 0, stream>>>(Sc, vT, den, attn);
  k_out<<<512, b256, 0, stream>>>(attn, woT, bo, out);
}

// Round 7
// 353.698 us; speedup vs baseline: 1.2300x; 1.0961x over previous
//
#include <hip/hip_runtime.h>
#include <hip/hip_bf16.h>

// ---------------------------------------------------------------------------
// LinearAttentionBlock: Q=phi(xWq+bq), K=phi(xWk+bk), V=xWv+bv
// scores = tril(Q K^T); out = ((scores V) / (rowsum(scores)+eps)) Wo + bo
// GEMM core: 2-phase double-buffered 128x128 tile, BK=32, 4 waves
//  + conflict-free LDS XOR swizzle (both-sides-consistent)
//  + natural N-fastest block order
//  + V-tile transposed via LDS retile (coalesced vT stores; r6 bug fixed:
//    read-back loop must cover 8 x 16B chunks per (e-row, half), not 4).
// ---------------------------------------------------------------------------

#define D_MODEL 1024
#define D_INNER 2048
#define SEQ     2048
#define NBATCH  4
#define MTOT    (NBATCH * SEQ)   // 8192

typedef __attribute__((ext_vector_type(8))) __bf16 bf16x8;
typedef __attribute__((ext_vector_type(4))) float  f32x4;
typedef __attribute__((ext_vector_type(8))) short  short8v;

__device__ __forceinline__ short f2bf(float f) {      // RNE f32 -> bf16 bits
  union { float f; unsigned u; } x; x.f = f;
  unsigned r = x.u + 0x7fffu + ((x.u >> 16) & 1u);
  return (short)(r >> 16);
}
__device__ __forceinline__ float bf2f(short s) {
  union { unsigned u; float f; } x; x.u = ((unsigned)(unsigned short)s) << 16;
  return x.f;
}

typedef const void __attribute__((address_space(1)))* as1cv;
typedef void __attribute__((address_space(3)))* as3v;

__device__ __forceinline__ void gload_lds16(const void* g, void* l) {
  __builtin_amdgcn_global_load_lds((as1cv)g, (as3v)l, 16, 0, 0);
}

__device__ __forceinline__ f32x4 mfma16(bf16x8 a, bf16x8 b, f32x4 c) {
  return __builtin_amdgcn_mfma_f32_16x16x32_bf16(a, b, c, 0, 0, 0);
}

// ---------------------------------------------------------------------------
// LDS tile: [128 rows][32 cols] bf16, 64 B rows, 4 x 16B slots per row.
// Swizzle: slot ^= (row>>1)&3  (involution). Reads 2-way-bank-aliased = free.
// ---------------------------------------------------------------------------
__device__ __forceinline__ bf16x8 ldsFrag(const short* base, int row, int kblk) {
  const int lb = row * 64 + kblk * 16;
  const int addr = lb ^ (((row >> 1) & 3) << 4);
  return *(const bf16x8*)((const char*)base + addr);
}

// Stage one 128x32 bf16 tile (8 KB) from row-major global [ldg] into LDS.
// 256 threads x 2 global_load_lds(16B). Linear LDS dest; swizzle realized by
// pre-swizzling the per-lane GLOBAL source column.
__device__ __forceinline__ void stage_tile(const short* __restrict__ g, int ldg,
                                           int rowBase, int k0,
                                           short* lds) {
  const int t  = threadIdx.x;                       // 0..255
  const int r0 = t >> 2;                            // rows 0..63 (+64 for 2nd)
  const int sc = (((t & 3) ^ ((t >> 3) & 3))) * 8;  // pre-swizzled col (elems)
  const short* s0 = g + (size_t)(rowBase + r0) * ldg + (k0 + sc);
  gload_lds16(s0, lds + t * 8);                           // rows 0..63
  gload_lds16(s0 + (size_t)64 * ldg, lds + t * 8 + 2048); // rows 64..127
}

// One BK=32 K-step: 8 x ds_read_b128 + 16 x MFMA from a staged 128x32 pair.
__device__ __forceinline__ void compute_step(const short* __restrict__ As,
                                             const short* __restrict__ Bs,
                                             f32x4 acc[4][4],
                                             int wr, int wc, int lrow, int kblk) {
  bf16x8 a[4], b[4];
#pragma unroll
  for (int m = 0; m < 4; ++m)
    a[m] = ldsFrag(As, wr * 64 + m * 16 + lrow, kblk);
#pragma unroll
  for (int n = 0; n < 4; ++n)
    b[n] = ldsFrag(Bs, wc * 64 + n * 16 + lrow, kblk);
#pragma unroll
  for (int m = 0; m < 4; ++m)
#pragma unroll
    for (int n = 0; n < 4; ++n)
      acc[m][n] = mfma16(a[m], b[n], acc[m][n]);
}

// A[M,K] row-major, B stored transposed [N,K] row-major. acc += A * B^T.
// (k1-k0) must be a positive multiple of 64. 2-phase double-buffered.
__device__ __forceinline__ void gemm_pipe(const short* __restrict__ A, int lda, int aRowBase,
                                          const short* __restrict__ B, int ldb, int bRowBase,
                                          int k0, int k1,
                                          short* As0, short* Bs0, short* As1, short* Bs1,
                                          f32x4 acc[4][4]) {
  const int lane = threadIdx.x & 63;
  const int wid  = threadIdx.x >> 6;
  const int wr = wid >> 1, wc = wid & 1;
  const int lrow = lane & 15, kblk = lane >> 4;
  stage_tile(A, lda, aRowBase, k0, As0);
  stage_tile(B, ldb, bRowBase, k0, Bs0);
  __syncthreads();
  for (int k = k0; k < k1; k += 64) {
    if (k + 32 < k1) {                       // prefetch k+32 into buf1
      stage_tile(A, lda, aRowBase, k + 32, As1);
      stage_tile(B, ldb, bRowBase, k + 32, Bs1);
    }
    compute_step(As0, Bs0, acc, wr, wc, lrow, kblk);
    __syncthreads();
    if (k + 64 < k1) {                       // prefetch k+64 into buf0
      stage_tile(A, lda, aRowBase, k + 64, As0);
      stage_tile(B, ldb, bRowBase, k + 64, Bs0);
    }
    compute_step(As1, Bs1, acc, wr, wc, lrow, kblk);
    __syncthreads();
  }
}

// Single 32 KB LDS block; the 4 stage buffers alias it, and epilogues may
// reuse the whole block after gemm_pipe (which ends with __syncthreads()).
#define GEMM_PRE                                           \
  __shared__ __align__(16) short smem[4 * 4096];           \
  short* As0 = smem;          short* Bs0 = smem + 4096;    \
  short* As1 = smem + 8192;   short* Bs1 = smem + 12288;   \
  f32x4 acc[4][4];                                         \
  _Pragma("unroll")                                        \
  for (int m = 0; m < 4; ++m)                              \
    _Pragma("unroll")                                      \
    for (int n = 0; n < 4; ++n) acc[m][n] = (f32x4){0.f, 0.f, 0.f, 0.f};

#define EPILOG_VARS                                        \
  const int lane = threadIdx.x & 63;                       \
  const int wid  = threadIdx.x >> 6;                       \
  const int wr = wid >> 1, wc = wid & 1;                   \
  const int lrow = lane & 15, kblk = lane >> 4;

// ---- fused QKV projection: N = 6144 (Q | K | V segments) ------------------
__global__ __launch_bounds__(256) void k_proj_qkv(const short* __restrict__ X,
                                                  const short* __restrict__ WT,
                                                  const float* __restrict__ bq,
                                                  const float* __restrict__ bk,
                                                  const float* __restrict__ bv,
                                                  short* __restrict__ Qm,
                                                  short* __restrict__ Km,
                                                  short* __restrict__ vT) {
  GEMM_PRE
  const int blockM = blockIdx.y * 128;
  const int blockN = blockIdx.x * 128;     // [0, 6144)
  gemm_pipe(X, D_MODEL, blockM, WT, D_MODEL, blockN, 0, D_MODEL,
            As0, Bs0, As1, Bs1, acc);
  EPILOG_VARS
  const int seg = blockN >> 11;            // 0=Q 1=K 2=V
  if (seg < 2) {
    const float* bias = (seg == 0) ? bq : bk;
    short* dstm = (seg == 0) ? Qm : Km;
#pragma unroll
    for (int m = 0; m < 4; ++m)
#pragma unroll
      for (int n = 0; n < 4; ++n) {
        const int e = (blockN & 2047) + wc * 64 + n * 16 + lrow;
        const float bvv = bias[e];
#pragma unroll
        for (int j = 0; j < 4; ++j) {
          const int row = blockM + wr * 64 + m * 16 + kblk * 4 + j;  // token
          float v = acc[m][n][j] + bvv;
          v = (v > 0.f) ? (v + 1.f) : __expf(v);      // elu(x)+1
          dstm[(size_t)row * D_INNER + e] = f2bf(v);
        }
      }
  } else {
    // V: transpose the 128x128 tile via LDS, then coalesced vT writes.
    // smem reused as a swizzled [128 e][128 m] bf16 transpose buffer:
    // physical byte = cl*256 + ((rl*2) ^ ((cl&7)<<5))  (bijective).
#pragma unroll
    for (int m = 0; m < 4; ++m)
#pragma unroll
      for (int n = 0; n < 4; ++n) {
        const int cl = wc * 64 + n * 16 + lrow;       // e-local
        const float bvv = bv[(blockN & 2047) + cl];
#pragma unroll
        for (int j = 0; j < 4; ++j) {
          const int rl = wr * 64 + m * 16 + kblk * 4 + j;  // token-local
          int byte = cl * 256 + rl * 2;
          byte ^= (cl & 7) << 5;                      // bank-spread writes
          *(short*)((char*)smem + byte) = f2bf(acc[m][n][j] + bvv);
        }
      }
    __syncthreads();
    const int b   = blockM >> 11;                     // batch
    const int mm0 = blockM & 2047;                    // token base in batch
    const int e0  = blockN & 2047;
    const int er  = threadIdx.x >> 1;                 // e-row 0..127
    const int hf  = threadIdx.x & 1;                  // half of the 128 tokens
    short* dst = vT + ((size_t)b * D_INNER + e0 + er) * SEQ + mm0 + hf * 64;
#pragma unroll
    for (int i = 0; i < 8; ++i) {                     // 8 x 16B = 64 tokens
      int byte = er * 256 + hf * 128 + i * 16;
      byte ^= (er & 7) << 5;
      ((short8v*)dst)[i] = *(const short8v*)((const char*)smem + byte);
    }
  }
}

// ---- scores = tril(Q K^T), bf16; dense triangular grid (no zero-fill) -----
__global__ __launch_bounds__(256) void k_qkt(const short* __restrict__ Q,
                                             const short* __restrict__ Kmat,
                                             short* __restrict__ S) {
  const int b = blockIdx.y;
  const int t = blockIdx.x;                // 0..135 -> (ib, jb<=ib)
  int ib = (int)((-1.0f + sqrtf(8.0f * (float)t + 1.0f)) * 0.5f);
  while ((ib + 1) * (ib + 2) / 2 <= t) ++ib;
  while (ib * (ib + 1) / 2 > t) --ib;
  const int jb = t - ib * (ib + 1) / 2;
  GEMM_PRE
  short* Sb = S + (size_t)b * SEQ * SEQ;
  gemm_pipe(Q + (size_t)b * SEQ * D_INNER, D_INNER, ib * 128,
            Kmat + (size_t)b * SEQ * D_INNER, D_INNER, jb * 128,
            0, D_INNER, As0, Bs0, As1, Bs1, acc);
  EPILOG_VARS
  const bool diag = (jb == ib);
#pragma unroll
  for (int m = 0; m < 4; ++m)
#pragma unroll
    for (int n = 0; n < 4; ++n) {
      const int col = jb * 128 + wc * 64 + n * 16 + lrow;       // j
#pragma unroll
      for (int j = 0; j < 4; ++j) {
        const int row = ib * 128 + wr * 64 + m * 16 + kblk * 4 + j;  // i
        float v = acc[m][n][j];
        if (diag && col > row) v = 0.f;
        Sb[(size_t)row * SEQ + col] = f2bf(v);
      }
    }
}

// ---- denominator: rowsum of valid (128-block prefix) scores + eps ---------
__global__ __launch_bounds__(256) void k_denom(const short* __restrict__ S,
                                               float* __restrict__ denom) {
  const int grow = blockIdx.x;                 // 0..8191
  const int b = grow >> 11, i = grow & 2047;
  const int limit = ((i >> 7) + 1) << 7;       // cols valid: [0, limit)
  const short* r = S + ((size_t)b * SEQ + i) * SEQ;
  const int tid = threadIdx.x;
  float s = 0.f;
  if (tid * 8 < limit) {
    short8v v = *(const short8v*)(r + tid * 8);
#pragma unroll
    for (int t = 0; t < 8; ++t) s += bf2f(v[t]);
  }
#pragma unroll
  for (int off = 32; off >= 1; off >>= 1) s += __shfl_down(s, off, 64);
  __shared__ float ws[4];
  if ((tid & 63) == 0) ws[tid >> 6] = s;
  __syncthreads();
  if (tid == 0) denom[grow] = ws[0] + ws[1] + ws[2] + ws[3] + 1e-6f;
}

// ---- attn = (S V) / denom, bf16; K truncated; heavy (large ib) first ------
__global__ __launch_bounds__(256) void k_av(const short* __restrict__ S,
                                            const short* __restrict__ VT,
                                            const float* __restrict__ denom,
                                            short* __restrict__ attn) {
  const int b = blockIdx.z;
  const int ib = 15 - blockIdx.y;          // heavy blocks dispatched first
  const int eb = blockIdx.x;
  GEMM_PRE
  gemm_pipe(S + (size_t)b * SEQ * SEQ, SEQ, ib * 128,
            VT + (size_t)b * (size_t)D_INNER * SEQ, SEQ, eb * 128,
            0, (ib + 1) * 128, As0, Bs0, As1, Bs1, acc);
  EPILOG_VARS
  const int blockM = ib * 128;
#pragma unroll
  for (int m = 0; m < 4; ++m)
#pragma unroll
    for (int j = 0; j < 4; ++j) {
      const int row = blockM + wr * 64 + m * 16 + kblk * 4 + j;  // token
      const float rcp = 1.0f / denom[b * SEQ + row];
#pragma unroll
      for (int n = 0; n < 4; ++n) {
        const int col = eb * 128 + wc * 64 + n * 16 + lrow;      // e
        attn[((size_t)(b * SEQ + row)) * D_INNER + col] = f2bf(acc[m][n][j] * rcp);
      }
    }
}

// ---- final: out = attn Wo + bo (fp32 out) ---------------------------------
__global__ __launch_bounds__(256) void k_out(const short* __restrict__ A,
                                             const short* __restrict__ WoT,
                                             const float* __restrict__ bo,
                                             float* __restrict__ out) {
  GEMM_PRE
  const int blockM = blockIdx.y * 128;
  const int blockN = blockIdx.x * 128;
  gemm_pipe(A, D_INNER, blockM, WoT, D_INNER, blockN, 0, D_INNER,
            As0, Bs0, As1, Bs1, acc);
  EPILOG_VARS
#pragma unroll
  for (int m = 0; m < 4; ++m)
#pragma unroll
    for (int n = 0; n < 4; ++n) {
      const int col = blockN + wc * 64 + n * 16 + lrow;
      const float bvv = bo[col];
#pragma unroll
      for (int j = 0; j < 4; ++j) {
        const int row = blockM + wr * 64 + m * 16 + kblk * 4 + j;
        out[(size_t)row * D_MODEL + col] = acc[m][n][j] + bvv;
      }
    }
}

// ---- converts -------------------------------------------------------------
__global__ void k_cvt(const float* __restrict__ in, short* __restrict__ out, int n4) {
  int i = blockIdx.x * blockDim.x + threadIdx.x;
  const int stride = gridDim.x * blockDim.x;
  for (; i < n4; i += stride) {
    float4 v = ((const float4*)in)[i];
    short4 o;
    o.x = f2bf(v.x); o.y = f2bf(v.y); o.z = f2bf(v.z); o.w = f2bf(v.w);
    ((short4*)out)[i] = o;
  }
}

// coalesced tiled transpose: in [R][C] fp32 -> out [C][R] bf16
// blockIdx.z selects among 3 equal-shaped weight matrices (Wq,Wk,Wv).
__global__ __launch_bounds__(256) void k_transpose3(const float* __restrict__ w0,
                                                    const float* __restrict__ w1,
                                                    const float* __restrict__ w2,
                                                    short* __restrict__ out,
                                                    int R, int C) {
  __shared__ float t[32][33];
  const float* in = (blockIdx.z == 0) ? w0 : (blockIdx.z == 1) ? w1 : w2;
  short* o = out + (size_t)blockIdx.z * R * C;
  const int c0 = blockIdx.x * 32, r0 = blockIdx.y * 32;
  const int tx = threadIdx.x & 31, ty = (threadIdx.x >> 5) * 4;
#pragma unroll
  for (int i = 0; i < 4; ++i)
    t[ty + i][tx] = in[(size_t)(r0 + ty + i) * C + (c0 + tx)];
  __syncthreads();
#pragma unroll
  for (int i = 0; i < 4; ++i)
    o[(size_t)(c0 + ty + i) * R + (r0 + tx)] = f2bf(t[tx][ty + i]);
}

__global__ __launch_bounds__(256) void k_transpose1(const float* __restrict__ in,
                                                    short* __restrict__ out,
                                                    int R, int C) {
  __shared__ float t[32][33];
  const int c0 = blockIdx.x * 32, r0 = blockIdx.y * 32;
  const int tx = threadIdx.x & 31, ty = (threadIdx.x >> 5) * 4;
#pragma unroll
  for (int i = 0; i < 4; ++i)
    t[ty + i][tx] = in[(size_t)(r0 + ty + i) * C + (c0 + tx)];
  __syncthreads();
#pragma unroll
  for (int i = 0; i < 4; ++i)
    out[(size_t)(c0 + ty + i) * R + (r0 + tx)] = f2bf(t[tx][ty + i]);
}

// ---------------------------------------------------------------------------
extern "C" void kernel_launch(void* const* d_in, const int* in_sizes, int n_in,
                              void* d_out, int out_size, void* d_ws, size_t ws_size,
                              hipStream_t stream) {
  const float* x  = (const float*)d_in[0];
  const float* Wq = (const float*)d_in[1];
  const float* bq = (const float*)d_in[2];
  const float* Wk = (const float*)d_in[3];
  const float* bk = (const float*)d_in[4];
  const float* Wv = (const float*)d_in[5];
  const float* bv = (const float*)d_in[6];
  const float* Wo = (const float*)d_in[7];
  const float* bo = (const float*)d_in[8];
  float* out = (float*)d_out;

  // workspace layout (bf16 shorts unless noted); total ~201.4 MB
  short* xb    = (short*)d_ws;                          // [8192][1024]
  short* wqkvT = xb    + (size_t)MTOT * D_MODEL;        // [6144][1024] (Q|K|V)
  short* woT   = wqkvT + (size_t)3 * D_INNER * D_MODEL; // [1024][2048]
  short* Qm    = woT   + (size_t)D_MODEL * D_INNER;     // [8192][2048]
  short* Km    = Qm    + (size_t)MTOT * D_INNER;
  short* vT    = Km    + (size_t)MTOT * D_INNER;        // [4][2048 e][2048 m]
  short* Sc    = vT    + (size_t)MTOT * D_INNER;        // [4][2048][2048]
  short* attn  = Sc    + (size_t)NBATCH * SEQ * SEQ;    // [8192][2048]
  float* den   = (float*)(attn + (size_t)MTOT * D_INNER);  // [8192]

  dim3 b256(256);
  k_cvt<<<2048, b256, 0, stream>>>(x, xb, MTOT * D_MODEL / 4);
  // W[1024][2048] -> WT[2048][1024] x3 (Q,K,V) in one launch
  k_transpose3<<<dim3(64, 32, 3), b256, 0, stream>>>(Wq, Wk, Wv, wqkvT, 1024, 2048);
  // Wo[2048][1024] -> WoT[1024][2048]
  k_transpose1<<<dim3(32, 64), b256, 0, stream>>>(Wo, woT, 2048, 1024);

  k_proj_qkv<<<dim3(48, 64), b256, 0, stream>>>(xb, wqkvT, bq, bk, bv, Qm, Km, vT);

  k_qkt<<<dim3(136, NBATCH), b256, 0, stream>>>(Qm, Km, Sc);
  k_denom<<<MTOT, b256, 0, stream>>>(Sc, den);
  k_av<<<dim3(16, 16, NBATCH), b256, 0, stream>>>(Sc, vT, den, attn);
  k_out<<<dim3(8, 64), b256, 0, stream>>>(attn, woT, bo, out);
}